// Round 5
// baseline (508.519 us; speedup 1.0000x reference)
//
#include <hip/hip_runtime.h>
#include <stdint.h>

typedef unsigned short u16;
typedef __attribute__((ext_vector_type(8))) short short8;
typedef __attribute__((ext_vector_type(4))) float f32x4;
typedef __attribute__((ext_vector_type(16))) float f32x16;

#define NCTX 4096
#define NTGT 2048
#define DMODEL 1024
#define NH 16
#define HD 64

typedef const __attribute__((address_space(1))) uint32_t g_u32;
typedef __attribute__((address_space(3))) uint32_t lds_u32;

__device__ inline u16 f2b(float f) {
  unsigned r;
  asm("v_cvt_pk_bf16_f32 %0, %1, %1" : "=v"(r) : "v"(f));
  return (u16)r;
}
__device__ inline uint32_t pk2(float lo, float hi_) {
  uint32_t r;
  asm("v_cvt_pk_bf16_f32 %0, %1, %2" : "=v"(r) : "v"(lo), "v"(hi_));
  return r;
}

// ---------------- f32 -> bf16 conversion ----------------
__global__ void cvt_bf16(const float* __restrict__ in, u16* __restrict__ out, int n4) {
  int i = blockIdx.x * blockDim.x + threadIdx.x;
  if (i >= n4) return;
  const float4 v = ((const float4*)in)[i];
  ((uint2*)out)[i] = make_uint2(pk2(v.x, v.y), pk2(v.z, v.w));
}

// ---------------- generic C = A * B^T  (bf16 in, f32 accum) ----------------
// MODE 1: K-writer; Ck is pre-scaled by beta*log2e (used only for scores).
template<int MODE>
__global__ __launch_bounds__(256) void gemm_bt(
    const u16* __restrict__ A, const u16* __restrict__ B,
    float* __restrict__ Cf, u16* __restrict__ Ck, u16* __restrict__ Ckt,
    int M, int N, int Kd) {
  const int bm = blockIdx.x % (M >> 6);
  const int bn = blockIdx.x / (M >> 6);
  const int w = threadIdx.x >> 6, l = threadIdx.x & 63;
  const int lg = l >> 4, lm = l & 15;
  const int m0 = (bm << 6) + (w << 4);
  const int n0 = bn << 6;

  const u16* Ar = A + (size_t)(m0 + lm) * Kd;
  f32x4 acc[4] = {};

  for (int kd = 0; kd < Kd; kd += 64) {
    short8 a0 = *(const short8*)(Ar + kd + lg * 8);
    short8 a1 = *(const short8*)(Ar + kd + 32 + lg * 8);
#pragma unroll
    for (int nf = 0; nf < 4; ++nf) {
      const u16* Br = B + (size_t)(n0 + nf * 16 + lm) * Kd + kd + lg * 8;
      short8 b0 = *(const short8*)(Br);
      short8 b1 = *(const short8*)(Br + 32);
      acc[nf] = __builtin_amdgcn_mfma_f32_16x16x32_bf16(a0, b0, acc[nf], 0, 0, 0);
      acc[nf] = __builtin_amdgcn_mfma_f32_16x16x32_bf16(a1, b1, acc[nf], 0, 0, 0);
    }
  }

  if (MODE == 0) {
#pragma unroll
    for (int nf = 0; nf < 4; ++nf)
#pragma unroll
      for (int r = 0; r < 4; ++r)
        Cf[(size_t)(m0 + lg * 4 + r) * N + (n0 + nf * 16 + lm)] = acc[nf][r];
  } else {
    const float BL2E = 0.125f * 1.44269504088896340736f;
#pragma unroll
    for (int nf = 0; nf < 4; ++nf) {
      int n = n0 + nf * 16 + lm;
      int h = n >> 6, z = n & 63;
#pragma unroll
      for (int r = 0; r < 4; ++r) {
        int k = m0 + lg * 4 + r;
        Ck[((size_t)h * NCTX + k) * HD + z] = f2b(acc[nf][r] * BL2E);
        Ckt[((size_t)h * HD + z) * NCTX + k] = f2b(acc[nf][r]);
      }
    }
  }
}

// ---------------- 5-step energy attention ----------------
// 512 blocks = 16 heads x 32 q-tiles of 64 rows; 4 waves = (kh, qh) quadrants
// of the 64x64 swapped-St tile. Shared 64-k tile (K 8KB + Kt 8KB, 128B rows,
// blk^(row&7) swizzle) double-buffered; raw s_barrier + per-wave counted
// vmcnt keeps prefetch in flight across barriers. Merge scratch aliases sT.
__global__ __launch_bounds__(256, 4) void attn5(
    const u16* __restrict__ Kbf,   // [NH][NCTX][HD], pre-scaled by beta*log2e
    const u16* __restrict__ Ktb,   // [NH][HD][NCTX]
    const float* __restrict__ Qf,  // [NTGT][DMODEL]
    u16* __restrict__ Qob) {       // [NTGT][DMODEL] bf16
  __shared__ u16 sT[2][8192];      // [buf][ K 64x64 | Kt 64x64 ]
  __shared__ float lbuf[2][32];
  __shared__ float lfin[2][32];

  const int bid = blockIdx.x;
  const int h  = ((bid & 7) << 1) | ((bid >> 3) & 1);
  const int qt = bid >> 4;
  const int w = threadIdx.x >> 6, l = threadIdx.x & 63;
  const int ln = l & 31, hi = l >> 5;
  const int qh = w & 1, kh = w >> 1;
  const int q0 = qt * 64 + qh * 32;

  const u16* Kh  = Kbf + (size_t)h * NCTX * HD;
  const u16* Kth = Ktb + (size_t)h * HD * NCTX;

  // staging: wave w owns rows [w*16, w*16+16) of both parts; 8 rows per load
  const int srow = l >> 3;                     // 0..7
  const int sblk = ((l & 7) ^ srow) << 3;      // inverse swizzle on source
  const u16* srcK  = Kh  + (size_t)(w * 16 + srow) * HD + sblk;
  const u16* srcKt = Kth + (size_t)(w * 16 + srow) * NCTX + sblk;

  auto STAGE = [&](int b, int t) {
    const u16* gk = srcK + (size_t)t * 64 * HD;
    const u16* gt = srcKt + t * 64;
    __builtin_amdgcn_global_load_lds((g_u32*)gk,                      (lds_u32*)&sT[b][w * 1024],        16, 0, 0);
    __builtin_amdgcn_global_load_lds((g_u32*)(gk + 8 * HD),           (lds_u32*)&sT[b][w * 1024 + 512],  16, 0, 0);
    __builtin_amdgcn_global_load_lds((g_u32*)gt,                      (lds_u32*)&sT[b][4096 + w * 1024], 16, 0, 0);
    __builtin_amdgcn_global_load_lds((g_u32*)(gt + (size_t)8 * NCTX), (lds_u32*)&sT[b][4096 + w * 1024 + 512], 16, 0, 0);
  };

  // ---- Q B-frags: lane q=ln, z = zc*16 + 8*hi + e ----
  short8 qfrag[4];
  {
    const float* qp = Qf + (size_t)(q0 + ln) * DMODEL + h * HD + hi * 8;
#pragma unroll
    for (int zc = 0; zc < 4; ++zc) {
      float4 f0 = *(const float4*)(qp + zc * 16);
      float4 f1 = *(const float4*)(qp + zc * 16 + 4);
      union { short8 s; uint32_t u[4]; } t;
      t.u[0] = pk2(f0.x, f0.y); t.u[1] = pk2(f0.z, f0.w);
      t.u[2] = pk2(f1.x, f1.y); t.u[3] = pk2(f1.z, f1.w);
      qfrag[zc] = t.s;
    }
  }
  // ---- q state f32, C-layout (kh==0 waves maintain) ----
  float qreg[2][16];
#pragma unroll
  for (int zb = 0; zb < 2; ++zb)
#pragma unroll
    for (int rr = 0; rr < 16; ++rr) {
      int qq = (rr & 3) + 8 * (rr >> 2) + 4 * hi;
      qreg[zb][rr] = Qf[(size_t)(q0 + qq) * DMODEL + h * HD + zb * 32 + ln];
    }

  STAGE(0, 0);

  for (int step = 0; step < 5; ++step) {
    f32x16 acc0 = {}, acc1 = {};
    float lrow = 0.f;

#pragma unroll 2
    for (int t = 0; t < 64; ++t) {
      const int buf = t & 1;
      asm volatile("s_waitcnt vmcnt(0)" ::: "memory");  // own tile-t loads done
      __builtin_amdgcn_s_barrier();                     // everyone's tile-t done
      if (t < 63) STAGE(buf ^ 1, t + 1);                // prefetch across barrier
      const u16* tb = &sT[buf][0];

      // ---- St = K_half * Q^T (rows k, cols q=ln) ----
      f32x16 st = {};
#pragma unroll
      for (int zc = 0; zc < 4; ++zc) {
        short8 kf = *(const short8*)(tb + (kh * 32 + ln) * 64 + (((zc * 2 + hi) ^ (ln & 7)) << 3));
        st = __builtin_amdgcn_mfma_f32_32x32x16_bf16(kf, qfrag[zc], st, 0, 0, 0);
      }
      // ---- P = exp2(St) (scale pre-folded into K); pack; PV ----
#pragma unroll
      for (int kc = 0; kc < 2; ++kc) {
        float p0 = exp2f(st[8 * kc + 0]), p1 = exp2f(st[8 * kc + 1]);
        float p2 = exp2f(st[8 * kc + 2]), p3 = exp2f(st[8 * kc + 3]);
        float p4 = exp2f(st[8 * kc + 4]), p5 = exp2f(st[8 * kc + 5]);
        float p6 = exp2f(st[8 * kc + 6]), p7 = exp2f(st[8 * kc + 7]);
        lrow += ((p0 + p1) + (p2 + p3)) + ((p4 + p5) + (p6 + p7));
        uint32_t a0 = pk2(p0, p1), a1 = pk2(p2, p3);
        uint32_t b0 = pk2(p4, p5), b1 = pk2(p6, p7);
        asm("v_permlane32_swap_b32 %0, %1" : "+v"(a0), "+v"(b0));
        asm("v_permlane32_swap_b32 %0, %1" : "+v"(a1), "+v"(b1));
        union { short8 s; uint32_t u[4]; } pa;
        pa.u[0] = a0; pa.u[1] = a1; pa.u[2] = b0; pa.u[3] = b1;
        const int sw = (((kh * 4 + kc * 2 + hi) ^ (ln & 7)) << 3);
        short8 v0 = *(const short8*)(tb + 4096 + ln * 64 + sw);
        short8 v1 = *(const short8*)(tb + 4096 + (32 + ln) * 64 + sw);
        acc0 = __builtin_amdgcn_mfma_f32_32x32x16_bf16(pa.s, v0, acc0, 0, 0, 0);
        acc1 = __builtin_amdgcn_mfma_f32_32x32x16_bf16(pa.s, v1, acc1, 0, 0, 0);
      }
    }

    __syncthreads();                       // all compute done; sT free
    lrow += __shfl_xor(lrow, 32);

    float* md = (float*)&sT[0][0] + qh * 2048;  // 8KB per qh, aliases buf0
    if (kh == 1) {
#pragma unroll
      for (int rr = 0; rr < 16; ++rr) {
        md[rr * 64 + l] = acc0[rr];
        md[(rr + 16) * 64 + l] = acc1[rr];
      }
      if (hi == 0) lbuf[qh][ln] = lrow;
    }
    __syncthreads();
    if (kh == 0) {
      float lt = lrow + lbuf[qh][ln];
      if (hi == 0) lfin[qh][ln] = lt;
#pragma unroll
      for (int rr = 0; rr < 16; ++rr) {
        acc0[rr] += md[rr * 64 + l];
        acc1[rr] += md[(rr + 16) * 64 + l];
      }
#pragma unroll
      for (int rr = 0; rr < 16; ++rr) {
        const int qq = (rr & 3) + 8 * (rr >> 2) + 4 * hi;
        const float sc = 0.1f / lfin[qh][qq];   // same-wave LDS, lgkm-ordered
        qreg[0][rr] += acc0[rr] * sc;
        qreg[1][rr] += acc1[rr] * sc;
      }
      if (step < 4) {
        u16* qs = &sT[1][qh * 2048];            // aliases buf1
#pragma unroll
        for (int zb = 0; zb < 2; ++zb)
#pragma unroll
          for (int rr = 0; rr < 16; ++rr) {
            const int qq = (rr & 3) + 8 * (rr >> 2) + 4 * hi;
            const int z = zb * 32 + ln;
            qs[qq * 64 + (((z >> 3) ^ (qq & 7)) << 3) + (z & 7)] = f2b(qreg[zb][rr]);
          }
      } else {
#pragma unroll
        for (int zb = 0; zb < 2; ++zb)
#pragma unroll
          for (int rr = 0; rr < 16; ++rr) {
            const int qq = (rr & 3) + 8 * (rr >> 2) + 4 * hi;
            Qob[(size_t)(q0 + qq) * DMODEL + h * HD + zb * 32 + ln] = f2b(qreg[zb][rr]);
          }
      }
    }
    if (step < 4) {
      __syncthreads();                     // qs visible to all waves
      const u16* qs = &sT[1][qh * 2048];
#pragma unroll
      for (int zc = 0; zc < 4; ++zc)
        qfrag[zc] = *(const short8*)(qs + ln * 64 + (((zc * 2 + hi) ^ (ln & 7)) << 3));
      __syncthreads();                     // reloads done before restaging
      STAGE(0, 0);
    }
  }
}

extern "C" void kernel_launch(void* const* d_in, const int* in_sizes, int n_in,
                              void* d_out, int out_size, void* d_ws, size_t ws_size,
                              hipStream_t stream) {
  const float* ctx = (const float*)d_in[0];
  const float* tgt = (const float*)d_in[1];
  const float* Wq  = (const float*)d_in[2];
  const float* Wk  = (const float*)d_in[3];
  const float* Wo  = (const float*)d_in[4];

  uint8_t* wp = (uint8_t*)d_ws;
  u16* ctxb = (u16*)wp; wp += (size_t)NCTX * DMODEL * 2;
  u16* tgtb = (u16*)wp; wp += (size_t)NTGT * DMODEL * 2;
  u16* wqb  = (u16*)wp; wp += (size_t)DMODEL * DMODEL * 2;
  u16* wkb  = (u16*)wp; wp += (size_t)DMODEL * DMODEL * 2;
  u16* wob  = (u16*)wp; wp += (size_t)DMODEL * DMODEL * 2;
  u16* Kbf  = (u16*)wp; wp += (size_t)NH * NCTX * HD * 2;
  u16* Ktb  = (u16*)wp; wp += (size_t)NH * HD * NCTX * 2;
  float* Qf = (float*)wp; wp += (size_t)NTGT * DMODEL * 4;
  u16* Qob  = (u16*)wp; wp += (size_t)NTGT * DMODEL * 2;

  auto cvt = [&](const float* in, u16* out, size_t n) {
    int n4 = (int)(n / 4);
    hipLaunchKernelGGL(cvt_bf16, dim3((n4 + 255) / 256), dim3(256), 0, stream, in, out, n4);
  };
  cvt(ctx, ctxb, (size_t)NCTX * DMODEL);
  cvt(tgt, tgtb, (size_t)NTGT * DMODEL);
  cvt(Wq, wqb, (size_t)DMODEL * DMODEL);
  cvt(Wk, wkb, (size_t)DMODEL * DMODEL);
  cvt(Wo, wob, (size_t)DMODEL * DMODEL);

  hipLaunchKernelGGL(gemm_bt<1>, dim3((NCTX / 64) * (DMODEL / 64)), dim3(256), 0, stream,
                     ctxb, wkb, (float*)nullptr, Kbf, Ktb, NCTX, DMODEL, DMODEL);
  hipLaunchKernelGGL(gemm_bt<0>, dim3((NTGT / 64) * (DMODEL / 64)), dim3(256), 0, stream,
                     tgtb, wqb, Qf, (u16*)nullptr, (u16*)nullptr, NTGT, DMODEL, DMODEL);
  hipLaunchKernelGGL(attn5, dim3(512), dim3(256), 0, stream, Kbf, Ktb, Qf, Qob);
  hipLaunchKernelGGL(gemm_bt<0>, dim3((NTGT / 64) * (DMODEL / 64)), dim3(256), 0, stream,
                     Qob, wob, (float*)d_out, (u16*)nullptr, (u16*)nullptr, NTGT, DMODEL, DMODEL);
}